// Round 15
// baseline (1150.326 us; speedup 1.0000x reference)
//
#include <hip/hip_runtime.h>
#include <hip/hip_bf16.h>
#include <cmath>

using bf16 = __hip_bfloat16;
typedef __bf16 bfx8 __attribute__((ext_vector_type(8)));
typedef float floatx4 __attribute__((ext_vector_type(4)));

__device__ __forceinline__ float b2f(bf16 v) { return __bfloat162float(v); }

// async global->LDS, 16B per lane. LDS dest must be wave-uniform base + lane*16.
__device__ __forceinline__ void gll16(const bf16* g, short* l) {
    void* gv = (void*)g;  // drop const
    __builtin_amdgcn_global_load_lds((__attribute__((address_space(1))) void*)gv,
                                     (__attribute__((address_space(3))) void*)l,
                                     16, 0, 0);
}

// ---- dtype detection: flag=1 -> inputs are f32, flag=0 -> inputs are bf16 --
__global__ void detect_dtype(const unsigned short* x, int* flag) {
    __shared__ int cnt[256];
    int t = threadIdx.x, bad = 0;
    for (int i = t; i < 8192; i += 256) {
        unsigned short lo = x[2 * i];
        int e = (lo >> 7) & 0xFF;
        if (e == 0xFF || e >= 0xC6 || (e != 0 && e <= 0x30)) bad++;
    }
    cnt[t] = bad; __syncthreads();
    if (t == 0) { int s = 0; for (int i = 0; i < 256; i++) s += cnt[i]; *flag = (s > 819) ? 1 : 0; }
}

__device__ __forceinline__ float rd(const void* src, long i, int f) {
    return f ? ((const float*)src)[i] : b2f(((const bf16*)src)[i]);
}

// raw (flag-dtype) -> bf16 scratch
__global__ void cvt_b16(const void* __restrict__ src, bf16* __restrict__ dst,
                        long n, const int* __restrict__ flag) {
    int f = *flag;
    long i = (long)blockIdx.x * 256 + threadIdx.x;
    if (i < n) dst[i] = __float2bfloat16(rd(src, i, f));
}

// tiled transpose-convert: WqT[h][d][e] = bf16(Wq[h][e][d]), same for Wk.
// grid (24,24,24): z = h*2 + which, 32x32 tiles, block 256 = 32x8.
__global__ __launch_bounds__(256) void tcvt(const void* __restrict__ q,
                                            const void* __restrict__ k,
                                            bf16* __restrict__ WqT, bf16* __restrict__ WkT,
                                            const int* __restrict__ flag) {
    const int f = *flag;
    __shared__ float tl[32][33];
    const int zh = blockIdx.z >> 1, w = blockIdx.z & 1;
    const void* src = w ? k : q;
    bf16* dst = w ? WkT : WqT;
    const int e0 = blockIdx.x * 32, d0 = blockIdx.y * 32;
    const int tx = threadIdx.x & 31, ty = threadIdx.x >> 5;
    const long base = (long)zh * 589824;
#pragma unroll
    for (int i = 0; i < 32; i += 8)
        tl[ty + i][tx] = rd(src, base + (long)(e0 + ty + i) * 768 + d0 + tx, f);
    __syncthreads();
#pragma unroll
    for (int i = 0; i < 32; i += 8)
        dst[base + (long)(d0 + ty + i) * 768 + e0 + tx] = __float2bfloat16(tl[tx][ty + i]);
}

// Wv rows straight into Wcomb rows [768,1536): Wcomb[h][768+e][d] = bf16(Wv[h][e][d])
__global__ void cvt_wv(const void* __restrict__ Wv, bf16* __restrict__ Wcomb,
                       const int* __restrict__ flag) {
    int f = *flag;
    long i = (long)blockIdx.x * 256 + threadIdx.x;   // 12*589824
    if (i >= 7077888L) return;
    long h = i / 589824, r = i - h * 589824;
    Wcomb[h * 1179648 + 589824 + r] = __float2bfloat16(rd(Wv, i, f));
}

// wpart[(s*12+h)*768+d] = sum_{e in s-th 96-chunk} Wk[h][e][d]*bq[h][e]
// grid (3,12,8)
__global__ __launch_bounds__(256) void mk_wvec_part(const void* __restrict__ Wk,
                                                    const void* __restrict__ bq,
                                                    float* __restrict__ wpart,
                                                    const int* __restrict__ flag) {
    int f = *flag;
    int h = blockIdx.y, s = blockIdx.z;
    int d = blockIdx.x * 256 + threadIdx.x;
    long base = (long)h * 589824;
    float acc = 0.f;
    const int e0 = s * 96;
    for (int e = e0; e < e0 + 96; e++)
        acc += rd(Wk, base + (long)e * 768 + d, f) * rd(bq, h * 768 + e, f);
    wpart[((long)s * 12 + h) * 768 + d] = acc;
}

// wvec[idx] = sum_s wpart[s][idx] / 14     grid (36)
__global__ __launch_bounds__(256) void mk_wvec_red(const float* __restrict__ wpart,
                                                   float* __restrict__ wvec) {
    int idx = blockIdx.x * 256 + threadIdx.x;   // 12*768 = 9216
    float s = 0.f;
#pragma unroll
    for (int i = 0; i < 8; i++) s += wpart[(long)i * 9216 + idx];
    wvec[idx] = s * (1.0f / 14.0f);
}

// Wmap [197,2364] -> bf16 padded [197, 12*224], zeros in pad columns
__global__ void pad_wmap(const void* wm, bf16* wp, const int* flag) {
    int f = *flag;
    int idx = blockIdx.x * 256 + threadIdx.x;   // 197*2688
    if (idx >= 197 * 2688) return;
    int t = idx / 2688, c = idx - t * 2688;
    int h = c / 224, j = c - h * 224;
    wp[idx] = __float2bfloat16(j < 197 ? rd(wm, (long)t * 2364 + h * 197 + j, f) : 0.f);
}

// LayerNorm-1 over D=768 -> bf16 hln, FUSED with vC dot-products:
// vC[(h*BC+b)*197+t] = dot(norm_row, wvec[h]).  grid = BC*197 blocks.
__global__ __launch_bounds__(256) void ln1_fused(const void* __restrict__ src,
                                                 const void* __restrict__ gw,
                                                 const void* __restrict__ bw,
                                                 bf16* __restrict__ dst,
                                                 float* __restrict__ vC,
                                                 const float* __restrict__ wvec,
                                                 long row0, int BC,
                                                 const int* __restrict__ flag)
{
    const int fl = *flag;
    const long gr = row0 + blockIdx.x;
    const int t = threadIdx.x;
    float v[3], s = 0.f, s2 = 0.f;
#pragma unroll
    for (int i = 0; i < 3; i++) {
        long gi = gr * 768 + t + 256 * i;
        float f0 = rd(src, gi, fl);
        v[i] = f0; s += f0; s2 += f0 * f0;
    }
#pragma unroll
    for (int o = 32; o; o >>= 1) { s += __shfl_xor(s, o); s2 += __shfl_xor(s2, o); }
    __shared__ float a1[4], a2[4];
    __shared__ float red[4];
    if ((t & 63) == 0) { a1[t >> 6] = s; a2[t >> 6] = s2; }
    __syncthreads();
    s = a1[0] + a1[1] + a1[2] + a1[3];
    s2 = a2[0] + a2[1] + a2[2] + a2[3];
    float mu = s * (1.f / 768.f);
    float var = s2 * (1.f / 768.f) - mu * mu;
    float rstd = rsqrtf(var + 1e-5f);
    float w[3];
#pragma unroll
    for (int i = 0; i < 3; i++) {
        int c = t + 256 * i;
        w[i] = (v[i] - mu) * rstd * rd(gw, c, fl) + rd(bw, c, fl);
        dst[(long)blockIdx.x * 768 + c] = __float2bfloat16(w[i]);
    }
    const int b = blockIdx.x / 197, tt = blockIdx.x - b * 197;
    for (int h = 0; h < 12; h++) {
        const float* wv = wvec + h * 768;
        float d = w[0] * wv[t] + w[1] * wv[t + 256] + w[2] * wv[t + 512];
#pragma unroll
        for (int o = 32; o; o >>= 1) d += __shfl_xor(d, o);
        if ((t & 63) == 0) red[t >> 6] = d;
        __syncthreads();
        if (t == 0) vC[((long)h * BC + b) * 197 + tt] = red[0] + red[1] + red[2] + red[3];
        __syncthreads();
    }
}

// reduce 4 split-K partials + bmap + x, then FUSED LayerNorm-2 -> h2 bf16.
__global__ __launch_bounds__(256) void red4ln(const float* __restrict__ part,
                                              const void* __restrict__ bmap,
                                              const void* __restrict__ x,
                                              const void* __restrict__ g2,
                                              const void* __restrict__ b2w,
                                              bf16* __restrict__ h2, long row0,
                                              int Mtot, const int* __restrict__ flag) {
    const int fl = *flag;
    const int gr = blockIdx.x;
    const int tt = gr % 197;
    const int t = threadIdx.x;
    float sv[3], s = 0.f, s2 = 0.f;
#pragma unroll
    for (int i = 0; i < 3; i++) {
        int c = t + 256 * i;
        long o = (long)gr * 768 + c;
        float v = part[o] + part[(long)Mtot * 768 + o]
                + part[2L * Mtot * 768 + o] + part[3L * Mtot * 768 + o]
                + rd(bmap, tt, fl) + rd(x, (row0 + gr) * 768 + c, fl);
        sv[i] = v; s += v; s2 += v * v;
    }
#pragma unroll
    for (int o = 32; o; o >>= 1) { s += __shfl_xor(s, o); s2 += __shfl_xor(s2, o); }
    __shared__ float a1[4], a2[4];
    if ((t & 63) == 0) { a1[t >> 6] = s; a2[t >> 6] = s2; }
    __syncthreads();
    s = a1[0] + a1[1] + a1[2] + a1[3];
    s2 = a2[0] + a2[1] + a2[2] + a2[3];
    float mu = s * (1.f / 768.f);
    float var = s2 * (1.f / 768.f) - mu * mu;
    float rstd = rsqrtf(var + 1e-5f);
#pragma unroll
    for (int i = 0; i < 3; i++) {
        int c = t + 256 * i;
        h2[(row0 + gr) * 768 + c] =
            __float2bfloat16((sv[i] - mu) * rstd * rd(g2, c, fl) + rd(b2w, c, fl));
    }
}

// reduce 4 split-K partials + b2 + h2 residual -> d_out (flag dtype). grid = Mtot
__global__ __launch_bounds__(256) void red6(const float* __restrict__ part,
                                            const void* __restrict__ b2,
                                            const bf16* __restrict__ h2,
                                            void* __restrict__ dout, long row0,
                                            int Mtot, const int* __restrict__ flag) {
    const int fl = *flag;
    const int gr = blockIdx.x;
    const int t = threadIdx.x;
#pragma unroll
    for (int i = 0; i < 3; i++) {
        int c = t + 256 * i;
        long o = (long)gr * 768 + c;
        float s = part[o] + part[(long)Mtot * 768 + o]
                + part[2L * Mtot * 768 + o] + part[3L * Mtot * 768 + o];
        float res = s + rd(b2, c, fl) + b2f(h2[o]);
        long ad = (row0 + gr) * 768 + c;
        if (fl) ((float*)dout)[ad] = res;
        else    ((bf16*)dout)[ad] = __float2bfloat16(res);
    }
}

// ---------------------------------------------------------------------------
// MFMA C = A @ B^T (+epilogue). 128x(JW*32) tile, BK=32, 256 thr (4 waves).
// 2-slot counted-vmcnt ring; kc-XOR swizzle pair; XCD bijective swizzle for
// modes 5/7/8.
// MODE 0: C bf16 [bz*hoff + m*768 + n] = val*scale            (Wcomb M build)
// MODE 5: C bf16 [m*3072+n] = gelu(val + raw1[r1off+n])       (mlp1)
// MODE 7: fused G1|vTg, N=1536. n<768: C=G1[bz][m][n]; else vTg scatter:
//         C3[(b_*768+nn)*2688 + hoff + bz*224 + t_] = val + bv[r1off+bz*768+nn]
// MODE 8: split-K partial: kc=bz%BCp,zb=bz/BCp; C f32 [(kc*hoff+zb*M+m)*768+n]
// MODE 9 (JW=8): fused scores+softmax -> attnT bf16 [bz][s=n][224: tt=m],
//         zero-padded for tt in [197,224)
// MODE 10: wattn = Wmap_h @ attnT^T. A=wmpad slice (lda 2688, col base
//         sA + hIn*224), B=attnT[z] (ldb 224), K=224. hIn=bz/BCp,bIn=bz%BCp.
//         C bf16 [(bIn*197+m)*2688 + hoff + hIn*224 + n] = n<197?val:0.
// ---------------------------------------------------------------------------
template <int MODE, int JW>
__global__ __launch_bounds__(256, JW == 8 ? 2 : 4) void mgemm(
    const bf16* __restrict__ Aall, const bf16* __restrict__ Ball,
    void* __restrict__ C, void* __restrict__ C2, void* __restrict__ C3,
    const void* __restrict__ raw1, long r1off, const void* __restrict__ raw2,
    const void* __restrict__ raw3,
    int M, int N, int K, int lda, int ldb, long sA, long sB,
    int hoff, int BCp, long row0, float scale, const int* __restrict__ flag)
{
    constexpr int NBC = JW / 2;
    __shared__ short As[2][4096];
    __shared__ short Bs[2][JW * 1024];

    const int tid  = threadIdx.x;
    const int wave = tid >> 6, lane = tid & 63;
    const int wy = wave >> 1, wx = wave & 1;
    const int lane16 = lane & 15, kg = lane >> 4;

    int bxx = blockIdx.x, byy = blockIdx.y, bzz = blockIdx.z;
    if constexpr (MODE == 5 || MODE == 7 || MODE == 8) {
        const int gx = gridDim.x, gyd = gridDim.y;
        const long nwg = (long)gx * gyd * gridDim.z;
        long flat = ((long)bzz * gyd + byy) * gx + bxx;
        const long q = nwg >> 3, r = nwg & 7;
        const long xcd = flat & 7, idx = flat >> 3;
        long nf = (xcd < r ? xcd * (q + 1) : r * (q + 1) + (xcd - r) * q) + idx;
        bxx = (int)(nf % gx); nf /= gx;
        byy = (int)(nf % gyd);
        bzz = (int)(nf / gyd);
    }
    const int m0 = byy * 128, n0 = bxx * (JW * 32);
    const int bz = bzz;

    long aOfs, bOfs;
    if constexpr (MODE == 8) {
        const int kc = bz % BCp, zb = bz / BCp;
        aOfs = (long)zb * sA + (long)kc * K;
        bOfs = (long)zb * sB + (long)kc * K;
    } else if constexpr (MODE == 9) {
        aOfs = (long)bz * sA;
        bOfs = (long)(bz % BCp) * sB;
    } else if constexpr (MODE == 10) {
        aOfs = sA + (long)(bz / BCp) * 224;
        bOfs = (long)bz * sB;
    } else {
        aOfs = (long)bz * sA;
        bOfs = (long)bz * sB;
    }
    const bf16* A = Aall + aOfs;
    const bf16* B = Ball + bOfs;

    const int c0 = tid, c1 = tid + 256;
    const long rA0 = min(m0 + (c0 >> 2), M - 1);
    const long rA1 = min(m0 + (c1 >> 2), M - 1);
    const int k0c = ((c0 & 3) ^ ((c0 >> 2) & 3)) * 8;
    const int k1c = ((c1 & 3) ^ ((c1 >> 2) & 3)) * 8;
    const int l0 = c0 * 8, l1 = c1 * 8;
    const bf16* pA0 = A + rA0 * lda + k0c;
    const bf16* pA1 = A + rA1 * lda + k1c;

    const bf16* pB[NBC];
    int lb[NBC];
#pragma unroll
    for (int q = 0; q < NBC; q++) {
        const int c = tid + q * 256;
        const int row = c >> 2;
        const int kc = ((c & 3) ^ (row & 3)) * 8;
        const long rB = min(n0 + row, N - 1);
        pB[q] = B + rB * ldb + kc;
        lb[q] = c * 8;
    }

    floatx4 acc[4][JW];
#pragma unroll
    for (int i = 0; i < 4; i++)
#pragma unroll
        for (int j = 0; j < JW; j++) acc[i][j] = (floatx4){0.f, 0.f, 0.f, 0.f};

    const int aoff = (wy * 64 + lane16) * 32 + (kg ^ (lane16 & 3)) * 8;
    const int boff = (wx * (JW * 16) + lane16) * 32 + (kg ^ (lane16 & 3)) * 8;

    const int nt = K >> 5;
    gll16(pA0, As[0] + l0);
    gll16(pA1, As[0] + l1);
#pragma unroll
    for (int q = 0; q < NBC; q++) gll16(pB[q], Bs[0] + lb[q]);

    for (int t = 0; t < nt; ++t) {
        if (t + 1 < nt) {
            short* An = As[(t + 1) & 1];
            short* Bn = Bs[(t + 1) & 1];
            const int ko = (t + 1) * 32;
            gll16(pA0 + ko, An + l0);
            gll16(pA1 + ko, An + l1);
#pragma unroll
            for (int q = 0; q < NBC; q++) gll16(pB[q] + ko, Bn + lb[q]);
            if constexpr (JW == 8)
                asm volatile("s_waitcnt vmcnt(6)" ::: "memory");
            else
                asm volatile("s_waitcnt vmcnt(4)" ::: "memory");
        } else {
            asm volatile("s_waitcnt vmcnt(0)" ::: "memory");
        }
        __builtin_amdgcn_s_barrier();
        const short* Ac = As[t & 1];
        const short* Bc = Bs[t & 1];
        bfx8 b[JW];
#pragma unroll
        for (int j = 0; j < JW; j++) b[j] = *(const bfx8*)(Bc + boff + j * 512);
        __builtin_amdgcn_s_setprio(1);
#pragma unroll
        for (int i = 0; i < 4; i++) {
            bfx8 a = *(const bfx8*)(Ac + aoff + i * 512);
#pragma unroll
            for (int j = 0; j < JW; j++)
                acc[i][j] = __builtin_amdgcn_mfma_f32_16x16x32_bf16(a, b[j], acc[i][j], 0, 0, 0);
        }
        __builtin_amdgcn_s_setprio(0);
        asm volatile("s_waitcnt lgkmcnt(0)" ::: "memory");
        __builtin_amdgcn_s_barrier();
    }

    const int mbase = m0 + wy * 64 + kg * 4;
    const int nbase = n0 + wx * (JW * 16) + lane16;

    if constexpr (MODE == 9) {
        // ---- fused softmax, TRANSPOSED output: attnT[s][tt], tt-pad zeroed --
        float* sM = (float*)As;
        float* sS = sM + 256;
        const float* vbias = (const float*)raw2;
        float vb[8];
#pragma unroll
        for (int j = 0; j < 8; j++) {
            const int n = nbase + j * 16;
            vb[j] = (n < 197) ? vbias[(long)bz * 197 + n] : 0.f;
        }
        // NOTE: softmax rows = m (query token tt), reduce over n (key s).
        float rmx[4][4], rsm[4][4];
#pragma unroll
        for (int i = 0; i < 4; i++)
#pragma unroll
            for (int r = 0; r < 4; r++) {
                float m = -1e30f;
#pragma unroll
                for (int j = 0; j < 8; j++) {
                    const int n = nbase + j * 16;
                    float v = (n < 197) ? acc[i][j][r] + vb[j] : -1e30f;
                    m = fmaxf(m, v);
                }
#pragma unroll
                for (int o = 8; o; o >>= 1) m = fmaxf(m, __shfl_xor(m, o));
                rmx[i][r] = m;
            }
        if (lane16 == 0) {
#pragma unroll
            for (int i = 0; i < 4; i++)
#pragma unroll
                for (int r = 0; r < 4; r++)
                    sM[wx * 128 + wy * 64 + i * 16 + kg * 4 + r] = rmx[i][r];
        }
        __syncthreads();
#pragma unroll
        for (int i = 0; i < 4; i++)
#pragma unroll
            for (int r = 0; r < 4; r++)
                rmx[i][r] = fmaxf(rmx[i][r],
                                  sM[(wx ^ 1) * 128 + wy * 64 + i * 16 + kg * 4 + r]);
#pragma unroll
        for (int i = 0; i < 4; i++)
#pragma unroll
            for (int r = 0; r < 4; r++) {
                float s = 0.f;
#pragma unroll
                for (int j = 0; j < 8; j++) {
                    const int n = nbase + j * 16;
                    float e = (n < 197) ? __expf(acc[i][j][r] + vb[j] - rmx[i][r]) : 0.f;
                    acc[i][j][r] = e;
                    s += e;
                }
#pragma unroll
                for (int o = 8; o; o >>= 1) s += __shfl_xor(s, o);
                rsm[i][r] = s;
            }
        if (lane16 == 0) {
#pragma unroll
            for (int i = 0; i < 4; i++)
#pragma unroll
                for (int r = 0; r < 4; r++)
                    sS[wx * 128 + wy * 64 + i * 16 + kg * 4 + r] = rsm[i][r];
        }
        __syncthreads();
#pragma unroll
        for (int i = 0; i < 4; i++)
#pragma unroll
            for (int r = 0; r < 4; r++)
                rsm[i][r] = 1.f / (rsm[i][r] +
                                   sS[(wx ^ 1) * 128 + wy * 64 + i * 16 + kg * 4 + r]);
        bf16* attnT = (bf16*)C;
#pragma unroll
        for (int j = 0; j < 8; j++) {
            const int n = nbase + j * 16;          // s (row of attnT)
            if (n >= 197) continue;
#pragma unroll
            for (int i = 0; i < 4; i++)
#pragma unroll
                for (int r = 0; r < 4; r++) {
                    const int m = mbase + i * 16 + r;   // tt (col of attnT)
                    if (m >= 224) continue;
                    float v = (m < 197) ? acc[i][j][r] * rsm[i][r] : 0.f;
                    attnT[((long)bz * 197 + n) * 224 + m] = __float2bfloat16(v);
                }
        }
    } else {
        const int fl = *flag;
        long qb = 0, vbb = 0, bb = 0;
        if constexpr (MODE == 7) {
            qb = (long)bz * M * 768;
            bb = r1off + (long)bz * 768;
        }
        long p8 = 0;
        if constexpr (MODE == 8) {
            const int kc = bz % BCp, zb = bz / BCp;
            p8 = (long)kc * hoff + (long)zb * M;
        }
        int hIn = 0, bIn = 0;
        if constexpr (MODE == 10) { hIn = bz / BCp; bIn = bz - hIn * BCp; }
#pragma unroll
        for (int i = 0; i < 4; i++) {
#pragma unroll
            for (int j = 0; j < JW; j++) {
                const int n = nbase + j * 16;
#pragma unroll
                for (int r = 0; r < 4; r++) {
                    const int m = mbase + i * 16 + r;
                    if constexpr (MODE == 10) {
                        if (m >= 197 || n >= 224) continue;
                        float v = (n < 197) ? acc[i][j][r] : 0.f;
                        ((bf16*)C)[((long)bIn * 197 + m) * 2688 + hoff + hIn * 224 + n] =
                            __float2bfloat16(v);
                        continue;
                    }
                    if (m >= M || n >= N) continue;
                    float val = acc[i][j][r];
                    if constexpr (MODE == 0) {
                        ((bf16*)C)[(long)bz * hoff + (long)m * 768 + n] =
                            __float2bfloat16(val * scale);
                    } else if constexpr (MODE == 5) {
                        float xv = val + rd(raw1, r1off + n, fl);
                        xv = 0.5f * xv * (1.f + erff(xv * 0.70710678f));
                        ((bf16*)C)[(long)m * 3072 + n] = __float2bfloat16(xv);
                    } else if constexpr (MODE == 7) {
                        if (n < 768) {
                            ((bf16*)C)[qb + (long)m * 768 + n] = __float2bfloat16(val);
                        } else {
                            const int nn = n - 768;
                            const int b_ = m / 197, t_ = m - b_ * 197;
                            ((bf16*)C3)[((long)b_ * 768 + nn) * 2688 + hoff + bz * 224 + t_] =
                                __float2bfloat16(val + rd(raw3, bb + nn, fl));
                        }
                    } else if constexpr (MODE == 8) {
                        ((float*)C)[(p8 + m) * 768 + n] = val;
                    }
                }
            }
        }
        (void)vbb;
    }
    (void)raw1; (void)raw3; (void)r1off; (void)row0; (void)scale; (void)C2; (void)C3;
}

extern "C" void kernel_launch(void* const* d_in, const int* in_sizes, int n_in,
                              void* d_out, int out_size, void* d_ws, size_t ws_size,
                              hipStream_t stream)
{
    const void* x    = d_in[0];
    const void* ln1g = d_in[1];
    const void* ln1b = d_in[2];
    const void* Wq   = d_in[3];
    const void* bq   = d_in[4];
    const void* Wk   = d_in[5];
    const void* bk   = d_in[6];
    const void* Wv   = d_in[7];
    const void* bv   = d_in[8];
    const void* Wmap = d_in[9];
    const void* bmap = d_in[10];
    const void* ln2g = d_in[11];
    const void* ln2b = d_in[12];
    const void* W1   = d_in[13];
    const void* b1   = d_in[14];
    const void* W2   = d_in[15];
    const void* b2   = d_in[16];
    (void)in_sizes; (void)n_in; (void)out_size; (void)bk;

    auto al   = [](size_t v) { return (v + 255) & ~(size_t)255; };
    auto cdiv = [](long a, long b) { return (int)((a + b - 1) / b); };

    // ---- reserved ----
    char* W = (char*)d_ws;
    size_t o = 0;
    auto take = [&](size_t bytes) -> char* { char* p = W + o; o += al(bytes); return p; };
    int*   flag  = (int*)take(256);
    bf16*  h2All = (bf16*)take(6304ull * 768 * 2);
    bf16*  wmpad = (bf16*)take(197ull * 2688 * 2);
    bf16*  Wcomb = (bf16*)take(12ull * 1536 * 768 * 2);
    float* wvec  = (float*)take(12ull * 768 * 4);
    float* wpart = (float*)take(8ull * 12 * 768 * 4);
    const size_t reservedB = o;
    char* arena = W + reservedB;

    const size_t preB = 2 * al(7077888ull * 2);

    // slab layout: [G1C | part4(union)] [wattnG] [attnT]; vTg separate.
    auto p1need = [&](int BCc, int HGc) -> size_t {
        size_t b = (size_t)BCc, g = (size_t)HGc;
        size_t sA_ = al(g * b * 302592);
        size_t sP_ = al(4ull * b * 605184);
        if (sA_ < sP_) sA_ = sP_;
        size_t slab = sA_ + al(b * 197 * 2688 * 2) + al(g * b * 88256);
        size_t body = al(b * 302592) + slab + al(12ull * b * 788) + al(b * 4128768ull);
        if (body < preB) body = preB;
        return reservedB + body;
    };
    int BC = 1, HG = 1;
    {   const int bs[6] = {32, 16, 8, 4, 2, 1};
        const int hs[6] = {12, 6, 4, 3, 2, 1};
        long best = -1;
        for (int i = 0; i < 6; i++)
            for (int j = 0; j < 6; j++) {
                long prod = (long)bs[i] * hs[j];
                if (p1need(bs[i], hs[j]) <= ws_size &&
                    (prod > best || (prod == best && hs[j] > HG))) {
                    best = prod; BC = bs[i]; HG = hs[j];
                }
            }
    }

    auto p2need = [&](int MCc) -> size_t {
        return reservedB + 2 * al(2359296ull * 2)
             + al((size_t)MCc * 3072 * 2)
             + al((size_t)MCc * 768 * 4 * 4);
    };
    int MC = 197;
    { const int ch[6] = {6304, 3152, 1576, 788, 394, 197};
      for (int i = 0; i < 6; i++) if (p2need(ch[i]) <= ws_size) { MC = ch[i]; break; } }

    // phase-1 buffers
    size_t po = 0;
    auto ptake = [&](size_t bytes) -> char* { char* p = arena + po; po += al(bytes); return p; };
    bf16*  hlnC = (bf16*)ptake((size_t)BC * 302592);
    size_t slabA = al((size_t)HG * BC * 302592);
    { size_t sP = al(4ull * BC * 605184); if (slabA < sP) slabA = sP; }
    size_t slabB = al((size_t)BC * 197 * 2688 * 2);
    size_t slabC = al((size_t)HG * BC * 88256);
    char*  slab    = ptake(slabA + slabB + slabC);
    bf16*  G1C     = (bf16*)slab;
    float* part4   = (float*)slab;                    // union with G1C (dead by map)
    bf16*  wattnG  = (bf16*)(slab + slabA);           // survives through map
    bf16*  attnC   = (bf16*)(slab + slabA + slabB);   // attnT
    float* vC      = (float*)ptake(12ull * BC * 788);
    bf16*  vTg     = (bf16*)ptake((size_t)BC * 4128768ull);  // [b][768][2688]
    bf16* WqT = (bf16*)arena;
    bf16* WkT = (bf16*)(arena + al(7077888ull * 2));
    size_t qo = 0;
    auto qtake = [&](size_t bytes) -> char* { char* p = arena + qo; qo += al(bytes); return p; };
    bf16*  W1b   = (bf16*)qtake(2359296ull * 2);
    bf16*  W2b   = (bf16*)qtake(2359296ull * 2);
    bf16*  gC    = (bf16*)qtake((size_t)MC * 3072 * 2);
    float* part2 = (float*)qtake((size_t)MC * 768 * 4 * 4);

    detect_dtype<<<1, 256, 0, stream>>>((const unsigned short*)x, flag);
    pad_wmap<<<cdiv(197L * 2688, 256), 256, 0, stream>>>(Wmap, wmpad, flag);
    tcvt<<<dim3(24, 24, 24), 256, 0, stream>>>(Wq, Wk, WqT, WkT, flag);
    mgemm<0, 4><<<dim3(6, 6, 12), 256, 0, stream>>>(WkT, WqT, Wcomb, nullptr, nullptr,
        nullptr, 0, nullptr, nullptr,
        768, 768, 768, 768, 768, 589824L, 589824L, 1179648, 0, 0, 1.0f / 14.0f, flag);
    cvt_wv<<<cdiv(7077888L, 256), 256, 0, stream>>>(Wv, Wcomb, flag);
    mk_wvec_part<<<dim3(3, 12, 8), 256, 0, stream>>>(Wk, bq, wpart, flag);
    mk_wvec_red<<<36, 256, 0, stream>>>(wpart, wvec);

    const int Mr = BC * 197;
    const int gy = cdiv(Mr, 128);
    for (int c0 = 0; c0 < 32; c0 += BC) {
        const long row0 = (long)c0 * 197;
        ln1_fused<<<Mr, 256, 0, stream>>>(x, ln1g, ln1b, hlnC, vC, wvec, row0, BC, flag);
        for (int hg = 0; hg < 12; hg += HG) {
            // fused G1|vTg projection: M=Mr, N=1536, K=768
            mgemm<7, 4><<<dim3(12, gy, HG), 256, 0, stream>>>(hlnC,
                Wcomb + (long)hg * 1179648, G1C, nullptr, vTg,
                nullptr, (long)hg * 768, nullptr, bv,
                Mr, 1536, 768, 768, 768, 0, 1179648L, hg * 224, 0, 0, 1.0f, flag);
            // fused scores+softmax -> attnT[z][s][tt] (tt-pad zeroed)
            mgemm<9, 8><<<dim3(1, 2, HG * BC), 256, 0, stream>>>(G1C, hlnC, attnC,
                nullptr, nullptr, nullptr, 0, vC + (long)hg * BC * 197, nullptr,
                197, 197, 768, 768, 768, 197L * 768, 197L * 768, 0, BC, 0, 1.0f, flag);
            // wattn[z] = Wmap_h @ attn[z] : M=197, N=197, K=224 -> wattnG slice
            mgemm<10, 4><<<dim3(2, 2, HG * BC), 256, 0, stream>>>(wmpad, attnC, wattnG,
                nullptr, nullptr, nullptr, 0, nullptr, nullptr,
                197, 197, 224, 2688, 224, (long)hg * 224, 197L * 224,
                hg * 224, BC, 0, 1.0f, flag);
        }
        // map: msa[b] = wattnG[b] @ vTg[b]^T, split-K x4; reduce + ln2 -> h2All
        mgemm<8, 4><<<dim3(6, 2, BC * 4), 256, 0, stream>>>(wattnG, vTg, part4,
            nullptr, nullptr, nullptr, 0, nullptr, nullptr,
            197, 768, 672, 2688, 2688, 197L * 2688, 768L * 2688, Mr, 4, 0, 1.0f, flag);
        red4ln<<<Mr, 256, 0, stream>>>(part4, bmap, x, ln2g, ln2b, h2All, row0, Mr, flag);
    }

    // ---- MLP phase ----
    cvt_b16<<<cdiv(2359296, 256), 256, 0, stream>>>(W1, W1b, 2359296, flag);
    cvt_b16<<<cdiv(2359296, 256), 256, 0, stream>>>(W2, W2b, 2359296, flag);
    for (int r0 = 0; r0 < 6304; r0 += MC) {
        const int gy2 = cdiv(MC, 128);
        mgemm<5, 4><<<dim3(24, gy2, 1), 256, 0, stream>>>(h2All + (long)r0 * 768, W1b, gC,
            nullptr, nullptr, b1, 0, nullptr, nullptr,
            MC, 3072, 768, 768, 768, 0, 0, 0, 0, 0, 1.0f, flag);
        // mlp2: split-K x4 partials, then reduce (+b2 + h2 residual) -> d_out
        mgemm<8, 4><<<dim3(6, gy2, 4), 256, 0, stream>>>(gC, W2b, part2,
            nullptr, nullptr, nullptr, 0, nullptr, nullptr,
            MC, 768, 768, 3072, 3072, 0, 0, MC, 4, 0, 1.0f, flag);
        red6<<<MC, 256, 0, stream>>>(part2, b2, h2All + (long)r0 * 768, d_out, r0, MC, flag);
    }
}

// Round 16
// 1057.376 us; speedup vs baseline: 1.0879x; 1.0879x over previous
//
#include <hip/hip_runtime.h>
#include <hip/hip_bf16.h>
#include <cmath>

using bf16 = __hip_bfloat16;
typedef __bf16 bfx8 __attribute__((ext_vector_type(8)));
typedef float floatx4 __attribute__((ext_vector_type(4)));

__device__ __forceinline__ float b2f(bf16 v) { return __bfloat162float(v); }

// async global->LDS, 16B per lane. LDS dest must be wave-uniform base + lane*16.
__device__ __forceinline__ void gll16(const bf16* g, short* l) {
    void* gv = (void*)g;  // drop const
    __builtin_amdgcn_global_load_lds((__attribute__((address_space(1))) void*)gv,
                                     (__attribute__((address_space(3))) void*)l,
                                     16, 0, 0);
}

// ---- dtype detection: flag=1 -> inputs are f32, flag=0 -> inputs are bf16 --
__global__ void detect_dtype(const unsigned short* x, int* flag) {
    __shared__ int cnt[256];
    int t = threadIdx.x, bad = 0;
    for (int i = t; i < 8192; i += 256) {
        unsigned short lo = x[2 * i];
        int e = (lo >> 7) & 0xFF;
        if (e == 0xFF || e >= 0xC6 || (e != 0 && e <= 0x30)) bad++;
    }
    cnt[t] = bad; __syncthreads();
    if (t == 0) { int s = 0; for (int i = 0; i < 256; i++) s += cnt[i]; *flag = (s > 819) ? 1 : 0; }
}

__device__ __forceinline__ float rd(const void* src, long i, int f) {
    return f ? ((const float*)src)[i] : b2f(((const bf16*)src)[i]);
}

// raw (flag-dtype) -> bf16 scratch
__global__ void cvt_b16(const void* __restrict__ src, bf16* __restrict__ dst,
                        long n, const int* __restrict__ flag) {
    int f = *flag;
    long i = (long)blockIdx.x * 256 + threadIdx.x;
    if (i < n) dst[i] = __float2bfloat16(rd(src, i, f));
}

// tiled transpose-convert: WqT[h][d][e] = bf16(Wq[h][e][d]), same for Wk.
// grid (24,24,24): z = h*2 + which, 32x32 tiles, block 256 = 32x8.
__global__ __launch_bounds__(256) void tcvt(const void* __restrict__ q,
                                            const void* __restrict__ k,
                                            bf16* __restrict__ WqT, bf16* __restrict__ WkT,
                                            const int* __restrict__ flag) {
    const int f = *flag;
    __shared__ float tl[32][33];
    const int zh = blockIdx.z >> 1, w = blockIdx.z & 1;
    const void* src = w ? k : q;
    bf16* dst = w ? WkT : WqT;
    const int e0 = blockIdx.x * 32, d0 = blockIdx.y * 32;
    const int tx = threadIdx.x & 31, ty = threadIdx.x >> 5;
    const long base = (long)zh * 589824;
#pragma unroll
    for (int i = 0; i < 32; i += 8)
        tl[ty + i][tx] = rd(src, base + (long)(e0 + ty + i) * 768 + d0 + tx, f);
    __syncthreads();
#pragma unroll
    for (int i = 0; i < 32; i += 8)
        dst[base + (long)(d0 + ty + i) * 768 + e0 + tx] = __float2bfloat16(tl[tx][ty + i]);
}

// Wv rows straight into Wcomb rows [768,1536): Wcomb[h][768+e][d] = bf16(Wv[h][e][d])
__global__ void cvt_wv(const void* __restrict__ Wv, bf16* __restrict__ Wcomb,
                       const int* __restrict__ flag) {
    int f = *flag;
    long i = (long)blockIdx.x * 256 + threadIdx.x;   // 12*589824
    if (i >= 7077888L) return;
    long h = i / 589824, r = i - h * 589824;
    Wcomb[h * 1179648 + 589824 + r] = __float2bfloat16(rd(Wv, i, f));
}

// wpart[(s*12+h)*768+d] = sum_{e in s-th 96-chunk} Wk[h][e][d]*bq[h][e]
// grid (3,12,8)
__global__ __launch_bounds__(256) void mk_wvec_part(const void* __restrict__ Wk,
                                                    const void* __restrict__ bq,
                                                    float* __restrict__ wpart,
                                                    const int* __restrict__ flag) {
    int f = *flag;
    int h = blockIdx.y, s = blockIdx.z;
    int d = blockIdx.x * 256 + threadIdx.x;
    long base = (long)h * 589824;
    float acc = 0.f;
    const int e0 = s * 96;
    for (int e = e0; e < e0 + 96; e++)
        acc += rd(Wk, base + (long)e * 768 + d, f) * rd(bq, h * 768 + e, f);
    wpart[((long)s * 12 + h) * 768 + d] = acc;
}

// wvec[idx] = sum_s wpart[s][idx] / 14     grid (36)
__global__ __launch_bounds__(256) void mk_wvec_red(const float* __restrict__ wpart,
                                                   float* __restrict__ wvec) {
    int idx = blockIdx.x * 256 + threadIdx.x;   // 12*768 = 9216
    float s = 0.f;
#pragma unroll
    for (int i = 0; i < 8; i++) s += wpart[(long)i * 9216 + idx];
    wvec[idx] = s * (1.0f / 14.0f);
}

// Wmap [197,2364] -> bf16 padded [197, 12*224], zeros in pad columns
__global__ void pad_wmap(const void* wm, bf16* wp, const int* flag) {
    int f = *flag;
    int idx = blockIdx.x * 256 + threadIdx.x;   // 197*2688
    if (idx >= 197 * 2688) return;
    int t = idx / 2688, c = idx - t * 2688;
    int h = c / 224, j = c - h * 224;
    wp[idx] = __float2bfloat16(j < 197 ? rd(wm, (long)t * 2364 + h * 197 + j, f) : 0.f);
}

// LayerNorm-1 over D=768 -> bf16 hln, FUSED with vC dot-products:
// vC[(h*BC+b)*197+t] = dot(norm_row, wvec[h]).  grid = BC*197 blocks.
// Single-barrier reduction: all 12 head dots shuffle-reduced in regs first.
__global__ __launch_bounds__(256) void ln1_fused(const void* __restrict__ src,
                                                 const void* __restrict__ gw,
                                                 const void* __restrict__ bw,
                                                 bf16* __restrict__ dst,
                                                 float* __restrict__ vC,
                                                 const float* __restrict__ wvec,
                                                 long row0, int BC,
                                                 const int* __restrict__ flag)
{
    const int fl = *flag;
    const long gr = row0 + blockIdx.x;
    const int t = threadIdx.x;
    float v[3], s = 0.f, s2 = 0.f;
#pragma unroll
    for (int i = 0; i < 3; i++) {
        long gi = gr * 768 + t + 256 * i;
        float f0 = rd(src, gi, fl);
        v[i] = f0; s += f0; s2 += f0 * f0;
    }
#pragma unroll
    for (int o = 32; o; o >>= 1) { s += __shfl_xor(s, o); s2 += __shfl_xor(s2, o); }
    __shared__ float a1[4], a2[4];
    __shared__ float red[12][4];
    if ((t & 63) == 0) { a1[t >> 6] = s; a2[t >> 6] = s2; }
    __syncthreads();
    s = a1[0] + a1[1] + a1[2] + a1[3];
    s2 = a2[0] + a2[1] + a2[2] + a2[3];
    float mu = s * (1.f / 768.f);
    float var = s2 * (1.f / 768.f) - mu * mu;
    float rstd = rsqrtf(var + 1e-5f);
    float w[3];
#pragma unroll
    for (int i = 0; i < 3; i++) {
        int c = t + 256 * i;
        w[i] = (v[i] - mu) * rstd * rd(gw, c, fl) + rd(bw, c, fl);
        dst[(long)blockIdx.x * 768 + c] = __float2bfloat16(w[i]);
    }
    // fused v[s] dots: all 12 heads reduced in registers, one barrier total
    float d[12];
#pragma unroll
    for (int h = 0; h < 12; h++) {
        const float* wv = wvec + h * 768;
        float dd = w[0] * wv[t] + w[1] * wv[t + 256] + w[2] * wv[t + 512];
#pragma unroll
        for (int o = 32; o; o >>= 1) dd += __shfl_xor(dd, o);
        d[h] = dd;
    }
    if ((t & 63) == 0) {
#pragma unroll
        for (int h = 0; h < 12; h++) red[h][t >> 6] = d[h];
    }
    __syncthreads();
    if (t < 12) {
        const int b = blockIdx.x / 197, tt = blockIdx.x - b * 197;
        vC[((long)t * BC + b) * 197 + tt] =
            red[t][0] + red[t][1] + red[t][2] + red[t][3];
    }
}

// reduce 4 split-K partials + bmap + x, then FUSED LayerNorm-2 -> h2 bf16.
__global__ __launch_bounds__(256) void red4ln(const float* __restrict__ part,
                                              const void* __restrict__ bmap,
                                              const void* __restrict__ x,
                                              const void* __restrict__ g2,
                                              const void* __restrict__ b2w,
                                              bf16* __restrict__ h2, long row0,
                                              int Mtot, const int* __restrict__ flag) {
    const int fl = *flag;
    const int gr = blockIdx.x;
    const int tt = gr % 197;
    const int t = threadIdx.x;
    float sv[3], s = 0.f, s2 = 0.f;
#pragma unroll
    for (int i = 0; i < 3; i++) {
        int c = t + 256 * i;
        long o = (long)gr * 768 + c;
        float v = part[o] + part[(long)Mtot * 768 + o]
                + part[2L * Mtot * 768 + o] + part[3L * Mtot * 768 + o]
                + rd(bmap, tt, fl) + rd(x, (row0 + gr) * 768 + c, fl);
        sv[i] = v; s += v; s2 += v * v;
    }
#pragma unroll
    for (int o = 32; o; o >>= 1) { s += __shfl_xor(s, o); s2 += __shfl_xor(s2, o); }
    __shared__ float a1[4], a2[4];
    if ((t & 63) == 0) { a1[t >> 6] = s; a2[t >> 6] = s2; }
    __syncthreads();
    s = a1[0] + a1[1] + a1[2] + a1[3];
    s2 = a2[0] + a2[1] + a2[2] + a2[3];
    float mu = s * (1.f / 768.f);
    float var = s2 * (1.f / 768.f) - mu * mu;
    float rstd = rsqrtf(var + 1e-5f);
#pragma unroll
    for (int i = 0; i < 3; i++) {
        int c = t + 256 * i;
        h2[(row0 + gr) * 768 + c] =
            __float2bfloat16((sv[i] - mu) * rstd * rd(g2, c, fl) + rd(b2w, c, fl));
    }
}

// reduce 4 split-K partials + b2 + h2 residual -> d_out (flag dtype). grid = Mtot
__global__ __launch_bounds__(256) void red6(const float* __restrict__ part,
                                            const void* __restrict__ b2,
                                            const bf16* __restrict__ h2,
                                            void* __restrict__ dout, long row0,
                                            int Mtot, const int* __restrict__ flag) {
    const int fl = *flag;
    const int gr = blockIdx.x;
    const int t = threadIdx.x;
#pragma unroll
    for (int i = 0; i < 3; i++) {
        int c = t + 256 * i;
        long o = (long)gr * 768 + c;
        float s = part[o] + part[(long)Mtot * 768 + o]
                + part[2L * Mtot * 768 + o] + part[3L * Mtot * 768 + o];
        float res = s + rd(b2, c, fl) + b2f(h2[o]);
        long ad = (row0 + gr) * 768 + c;
        if (fl) ((float*)dout)[ad] = res;
        else    ((bf16*)dout)[ad] = __float2bfloat16(res);
    }
}

// ---------------------------------------------------------------------------
// MFMA C = A @ B^T (+epilogue). 128x(JW*32) tile, BK=32, 256 thr (4 waves).
// 2-slot counted-vmcnt ring (r11/r14-proven best). kc-XOR swizzle pair;
// XCD bijective swizzle for modes 3/5/7/8.
// MODE 0: C bf16 [bz*hoff + m*768 + n] = val*scale            (Wcomb M build)
// MODE 3: hIn=bz/BCp,bIn=bz%BCp. C bf16 aoT[(bIn*768+n)*2688+hoff+hIn*224+m]
// MODE 5: C bf16 [m*3072+n] = gelu(val + raw1[r1off+n])       (mlp1)
// MODE 7: fused G1|vT, N=1536. n<768: C=G1[bz][m][n]; else C3=vT scatter+bv
// MODE 8: split-K partial: kc=bz%BCp,zb=bz/BCp; C f32 [(kc*hoff+zb*M+m)*768+n]
// MODE 9 (JW=8): fused scores+softmax -> attn bf16 [bz*197+m][224]
// ---------------------------------------------------------------------------
template <int MODE, int JW>
__global__ __launch_bounds__(256, JW == 8 ? 2 : 4) void mgemm(
    const bf16* __restrict__ Aall, const bf16* __restrict__ Ball,
    void* __restrict__ C, void* __restrict__ C2, void* __restrict__ C3,
    const void* __restrict__ raw1, long r1off, const void* __restrict__ raw2,
    const void* __restrict__ raw3,
    int M, int N, int K, int lda, int ldb, long sA, long sB,
    int hoff, int BCp, long row0, float scale, const int* __restrict__ flag)
{
    constexpr int NBC = JW / 2;
    __shared__ short As[2][4096];
    __shared__ short Bs[2][JW * 1024];

    const int tid  = threadIdx.x;
    const int wave = tid >> 6, lane = tid & 63;
    const int wy = wave >> 1, wx = wave & 1;
    const int lane16 = lane & 15, kg = lane >> 4;

    int bxx = blockIdx.x, byy = blockIdx.y, bzz = blockIdx.z;
    if constexpr (MODE == 3 || MODE == 5 || MODE == 7 || MODE == 8) {
        const int gx = gridDim.x, gyd = gridDim.y;
        const long nwg = (long)gx * gyd * gridDim.z;
        long flat = ((long)bzz * gyd + byy) * gx + bxx;
        const long q = nwg >> 3, r = nwg & 7;
        const long xcd = flat & 7, idx = flat >> 3;
        long nf = (xcd < r ? xcd * (q + 1) : r * (q + 1) + (xcd - r) * q) + idx;
        bxx = (int)(nf % gx); nf /= gx;
        byy = (int)(nf % gyd);
        bzz = (int)(nf / gyd);
    }
    const int m0 = byy * 128, n0 = bxx * (JW * 32);
    const int bz = bzz;

    long aOfs, bOfs;
    if constexpr (MODE == 8) {
        const int kc = bz % BCp, zb = bz / BCp;
        aOfs = (long)zb * sA + (long)kc * K;
        bOfs = (long)zb * sB + (long)kc * K;
    } else if constexpr (MODE == 9) {
        aOfs = (long)bz * sA;
        bOfs = (long)(bz % BCp) * sB;
    } else {
        aOfs = (long)bz * sA;
        bOfs = (long)bz * sB;
    }
    const bf16* A = Aall + aOfs;
    const bf16* B = Ball + bOfs;

    const int c0 = tid, c1 = tid + 256;
    const long rA0 = min(m0 + (c0 >> 2), M - 1);
    const long rA1 = min(m0 + (c1 >> 2), M - 1);
    const int k0c = ((c0 & 3) ^ ((c0 >> 2) & 3)) * 8;
    const int k1c = ((c1 & 3) ^ ((c1 >> 2) & 3)) * 8;
    const int l0 = c0 * 8, l1 = c1 * 8;
    const bf16* pA0 = A + rA0 * lda + k0c;
    const bf16* pA1 = A + rA1 * lda + k1c;

    const bf16* pB[NBC];
    int lb[NBC];
#pragma unroll
    for (int q = 0; q < NBC; q++) {
        const int c = tid + q * 256;
        const int row = c >> 2;
        const int kc = ((c & 3) ^ (row & 3)) * 8;
        const long rB = min(n0 + row, N - 1);
        pB[q] = B + rB * ldb + kc;
        lb[q] = c * 8;
    }

    floatx4 acc[4][JW];
#pragma unroll
    for (int i = 0; i < 4; i++)
#pragma unroll
        for (int j = 0; j < JW; j++) acc[i][j] = (floatx4){0.f, 0.f, 0.f, 0.f};

    const int aoff = (wy * 64 + lane16) * 32 + (kg ^ (lane16 & 3)) * 8;
    const int boff = (wx * (JW * 16) + lane16) * 32 + (kg ^ (lane16 & 3)) * 8;

    const int nt = K >> 5;
    gll16(pA0, As[0] + l0);
    gll16(pA1, As[0] + l1);
#pragma unroll
    for (int q = 0; q < NBC; q++) gll16(pB[q], Bs[0] + lb[q]);

    for (int t = 0; t < nt; ++t) {
        if (t + 1 < nt) {
            short* An = As[(t + 1) & 1];
            short* Bn = Bs[(t + 1) & 1];
            const int ko = (t + 1) * 32;
            gll16(pA0 + ko, An + l0);
            gll16(pA1 + ko, An + l1);
#pragma unroll
            for (int q = 0; q < NBC; q++) gll16(pB[q] + ko, Bn + lb[q]);
            if constexpr (JW == 8)
                asm volatile("s_waitcnt vmcnt(6)" ::: "memory");
            else
                asm volatile("s_waitcnt vmcnt(4)" ::: "memory");
        } else {
            asm volatile("s_waitcnt vmcnt(0)" ::: "memory");
        }
        __builtin_amdgcn_s_barrier();
        const short* Ac = As[t & 1];
        const short* Bc = Bs[t & 1];
        bfx8 b[JW];
#pragma unroll
        for (int j = 0; j < JW; j++) b[j] = *(const bfx8*)(Bc + boff + j * 512);
        __builtin_amdgcn_s_setprio(1);
#pragma unroll
        for (int i = 0; i < 4; i++) {
            bfx8 a = *(const bfx8*)(Ac + aoff + i * 512);
#pragma unroll
            for (int j = 0; j < JW; j++)
                acc[i][j] = __builtin_amdgcn_mfma_f32_16x16x32_bf16(a, b[j], acc[i][j], 0, 0, 0);
        }
        __builtin_amdgcn_s_setprio(0);
        asm volatile("s_waitcnt lgkmcnt(0)" ::: "memory");
        __builtin_amdgcn_s_barrier();
    }

    const int mbase = m0 + wy * 64 + kg * 4;
    const int nbase = n0 + wx * (JW * 16) + lane16;

    if constexpr (MODE == 9) {
        float* sM = (float*)As;
        float* sS = sM + 256;
        const float* vbias = (const float*)raw2;
        float vb[8];
#pragma unroll
        for (int j = 0; j < 8; j++) {
            const int n = nbase + j * 16;
            vb[j] = (n < 197) ? vbias[(long)bz * 197 + n] : 0.f;
        }
        float rmx[4][4], rsm[4][4];
#pragma unroll
        for (int i = 0; i < 4; i++)
#pragma unroll
            for (int r = 0; r < 4; r++) {
                float m = -1e30f;
#pragma unroll
                for (int j = 0; j < 8; j++) {
                    const int n = nbase + j * 16;
                    float v = (n < 197) ? acc[i][j][r] + vb[j] : -1e30f;
                    m = fmaxf(m, v);
                }
#pragma unroll
                for (int o = 8; o; o >>= 1) m = fmaxf(m, __shfl_xor(m, o));
                rmx[i][r] = m;
            }
        if (lane16 == 0) {
#pragma unroll
            for (int i = 0; i < 4; i++)
#pragma unroll
                for (int r = 0; r < 4; r++)
                    sM[wx * 128 + wy * 64 + i * 16 + kg * 4 + r] = rmx[i][r];
        }
        __syncthreads();
#pragma unroll
        for (int i = 0; i < 4; i++)
#pragma unroll
            for (int r = 0; r < 4; r++)
                rmx[i][r] = fmaxf(rmx[i][r],
                                  sM[(wx ^ 1) * 128 + wy * 64 + i * 16 + kg * 4 + r]);
#pragma unroll
        for (int i = 0; i < 4; i++)
#pragma unroll
            for (int r = 0; r < 4; r++) {
                float s = 0.f;
#pragma unroll
                for (int j = 0; j < 8; j++) {
                    const int n = nbase + j * 16;
                    float e = (n < 197) ? __expf(acc[i][j][r] + vb[j] - rmx[i][r]) : 0.f;
                    acc[i][j][r] = e;
                    s += e;
                }
#pragma unroll
                for (int o = 8; o; o >>= 1) s += __shfl_xor(s, o);
                rsm[i][r] = s;
            }
        if (lane16 == 0) {
#pragma unroll
            for (int i = 0; i < 4; i++)
#pragma unroll
                for (int r = 0; r < 4; r++)
                    sS[wx * 128 + wy * 64 + i * 16 + kg * 4 + r] = rsm[i][r];
        }
        __syncthreads();
#pragma unroll
        for (int i = 0; i < 4; i++)
#pragma unroll
            for (int r = 0; r < 4; r++)
                rsm[i][r] = 1.f / (rsm[i][r] +
                                   sS[(wx ^ 1) * 128 + wy * 64 + i * 16 + kg * 4 + r]);
        bf16* attn = (bf16*)C;
#pragma unroll
        for (int i = 0; i < 4; i++)
#pragma unroll
            for (int j = 0; j < 8; j++) {
                const int n = nbase + j * 16;
                if (n >= 224) continue;
#pragma unroll
                for (int r = 0; r < 4; r++) {
                    const int m = mbase + i * 16 + r;
                    if (m >= 197) continue;
                    attn[((long)bz * 197 + m) * 224 + n] =
                        __float2bfloat16(acc[i][j][r] * rsm[i][r]);
                }
            }
    } else {
        const int fl = *flag;
        int hIn = 0, bIn = 0;
        if constexpr (MODE == 3) { hIn = bz / BCp; bIn = bz - hIn * BCp; }
        long qb = 0, vbb = 0, bb = 0;
        if constexpr (MODE == 7) {
            qb = (long)bz * M * 768;
            vbb = (long)bz * (M / 197) * 768 * 224;
            bb = r1off + (long)bz * 768;
        }
        long p8 = 0;
        if constexpr (MODE == 8) {
            const int kc = bz % BCp, zb = bz / BCp;
            p8 = (long)kc * hoff + (long)zb * M;
        }
#pragma unroll
        for (int i = 0; i < 4; i++) {
#pragma unroll
            for (int j = 0; j < JW; j++) {
                const int n = nbase + j * 16;
                if constexpr (MODE == 3) {
                    const int mp = mbase + i * 16;
                    if (n < N && mp + 3 < M) {
                        bf16 tmp[4];
#pragma unroll
                        for (int r = 0; r < 4; r++) tmp[r] = __float2bfloat16(acc[i][j][r]);
                        *reinterpret_cast<short4*>(
                            &((bf16*)C)[((long)bIn * 768 + n) * 2688 + hoff + hIn * 224 + mp]) =
                            *reinterpret_cast<short4*>(tmp);
                        continue;
                    }
                }
#pragma unroll
                for (int r = 0; r < 4; r++) {
                    const int m = mbase + i * 16 + r;
                    if (m >= M || n >= N) continue;
                    float val = acc[i][j][r];
                    if constexpr (MODE == 0) {
                        ((bf16*)C)[(long)bz * hoff + (long)m * 768 + n] =
                            __float2bfloat16(val * scale);
                    } else if constexpr (MODE == 3) {
                        ((bf16*)C)[((long)bIn * 768 + n) * 2688 + hoff + hIn * 224 + m] =
                            __float2bfloat16(val);
                    } else if constexpr (MODE == 5) {
                        float xv = val + rd(raw1, r1off + n, fl);
                        xv = 0.5f * xv * (1.f + erff(xv * 0.70710678f));
                        ((bf16*)C)[(long)m * 3072 + n] = __float2bfloat16(xv);
                    } else if constexpr (MODE == 7) {
                        if (n < 768) {
                            ((bf16*)C)[qb + (long)m * 768 + n] = __float2bfloat16(val);
                        } else {
                            const int nn = n - 768;
                            const int b_ = m / 197, t_ = m - b_ * 197;
                            ((bf16*)C3)[vbb + ((long)b_ * 768 + nn) * 224 + t_] =
                                __float2bfloat16(val + rd(raw3, bb + nn, fl));
                        }
                    } else if constexpr (MODE == 8) {
                        ((float*)C)[(p8 + m) * 768 + n] = val;
                    }
                }
            }
        }
    }
    (void)raw1; (void)raw3; (void)r1off; (void)row0; (void)scale; (void)C2; (void)C3;
}

extern "C" void kernel_launch(void* const* d_in, const int* in_sizes, int n_in,
                              void* d_out, int out_size, void* d_ws, size_t ws_size,
                              hipStream_t stream)
{
    const void* x    = d_in[0];
    const void* ln1g = d_in[1];
    const void* ln1b = d_in[2];
    const void* Wq   = d_in[3];
    const void* bq   = d_in[4];
    const void* Wk   = d_in[5];
    const void* bk   = d_in[6];
    const void* Wv   = d_in[7];
    const void* bv   = d_in[8];
    const void* Wmap = d_in[9];
    const void* bmap = d_in[10];
    const void* ln2g = d_in[11];
    const void* ln2b = d_in[12];
    const void* W1   = d_in[13];
    const void* b1   = d_in[14];
    const void* W2   = d_in[15];
    const void* b2   = d_in[16];
    (void)in_sizes; (void)n_in; (void)out_size; (void)bk;

    auto al   = [](size_t v) { return (v + 255) & ~(size_t)255; };
    auto cdiv = [](long a, long b) { return (int)((a + b - 1) / b); };

    // ---- reserved ----
    char* W = (char*)d_ws;
    size_t o = 0;
    auto take = [&](size_t bytes) -> char* { char* p = W + o; o += al(bytes); return p; };
    int*   flag  = (int*)take(256);
    bf16*  h2All = (bf16*)take(6304ull * 768 * 2);
    bf16*  wmpad = (bf16*)take(197ull * 2688 * 2);
    bf16*  Wcomb = (bf16*)take(12ull * 1536 * 768 * 2);
    float* wvec  = (float*)take(12ull * 768 * 4);
    float* wpart = (float*)take(8ull * 12 * 768 * 4);
    const size_t reservedB = o;
    char* arena = W + reservedB;

    const size_t preB = 2 * al(7077888ull * 2);

    auto p1need = [&](int BCc, int HGc) -> size_t {
        size_t b = (size_t)BCc, g = (size_t)HGc;
        size_t slab = al(g * b * 302592) + al(g * b * 344064) + al(g * b * 88256);
        size_t part = al(4ull * b * 605184);
        if (slab < part) slab = part;
        size_t body = al(b * 302592) + slab + al(12ull * b * 788) + al(b * 4128768ull);
        if (body < preB) body = preB;
        return reservedB + body;
    };
    int BC = 1, HG = 1;
    {   const int bs[6] = {32, 16, 8, 4, 2, 1};
        const int hs[6] = {12, 6, 4, 3, 2, 1};
        long best = -1;
        for (int i = 0; i < 6; i++)
            for (int j = 0; j < 6; j++) {
                long prod = (long)bs[i] * hs[j];
                if (p1need(bs[i], hs[j]) <= ws_size &&
                    (prod > best || (prod == best && hs[j] > HG))) {
                    best = prod; BC = bs[i]; HG = hs[j];
                }
            }
    }

    auto p2need = [&](int MCc) -> size_t {
        return reservedB + 2 * al(2359296ull * 2)
             + al((size_t)MCc * 3072 * 2)
             + al((size_t)MCc * 768 * 4 * 4);
    };
    int MC = 197;
    { const int ch[6] = {6304, 3152, 1576, 788, 394, 197};
      for (int i = 0; i < 6; i++) if (p2need(ch[i]) <= ws_size) { MC = ch[i]; break; } }

    // phase-1 buffers
    size_t po = 0;
    auto ptake = [&](size_t bytes) -> char* { char* p = arena + po; po += al(bytes); return p; };
    bf16*  hlnC = (bf16*)ptake((size_t)BC * 302592);
    size_t slabA = al((size_t)HG * BC * 302592);
    size_t slabB = al((size_t)HG * BC * 344064);
    size_t slabC = al((size_t)HG * BC * 88256);
    size_t slabT = slabA + slabB + slabC;
    { size_t part = al(4ull * BC * 605184); if (slabT < part) slabT = part; }
    char*  slab    = ptake(slabT);
    bf16*  G1C     = (bf16*)slab;
    bf16*  vTC     = (bf16*)(slab + slabA);
    bf16*  attnC   = (bf16*)(slab + slabA + slabB);
    float* part4   = (float*)slab;
    float* vC      = (float*)ptake(12ull * BC * 788);
    bf16*  aoTg    = (bf16*)ptake((size_t)BC * 4128768ull);
    bf16* WqT = (bf16*)arena;
    bf16* WkT = (bf16*)(arena + al(7077888ull * 2));
    size_t qo = 0;
    auto qtake = [&](size_t bytes) -> char* { char* p = arena + qo; qo += al(bytes); return p; };
    bf16*  W1b   = (bf16*)qtake(2359296ull * 2);
    bf16*  W2b   = (bf16*)qtake(2359296ull * 2);
    bf16*  gC    = (bf16*)qtake((size_t)MC * 3072 * 2);
    float* part2 = (float*)qtake((size_t)MC * 768 * 4 * 4);

    detect_dtype<<<1, 256, 0, stream>>>((const unsigned short*)x, flag);
    pad_wmap<<<cdiv(197L * 2688, 256), 256, 0, stream>>>(Wmap, wmpad, flag);
    tcvt<<<dim3(24, 24, 24), 256, 0, stream>>>(Wq, Wk, WqT, WkT, flag);
    mgemm<0, 4><<<dim3(6, 6, 12), 256, 0, stream>>>(WkT, WqT, Wcomb, nullptr, nullptr,
        nullptr, 0, nullptr, nullptr,
        768, 768, 768, 768, 768, 589824L, 589824L, 1179648, 0, 0, 1.0f / 14.0f, flag);
    cvt_wv<<<cdiv(7077888L, 256), 256, 0, stream>>>(Wv, Wcomb, flag);
    mk_wvec_part<<<dim3(3, 12, 8), 256, 0, stream>>>(Wk, bq, wpart, flag);
    mk_wvec_red<<<36, 256, 0, stream>>>(wpart, wvec);

    const int Mr = BC * 197;
    const int gy = cdiv(Mr, 128);
    for (int c0 = 0; c0 < 32; c0 += BC) {
        const long row0 = (long)c0 * 197;
        ln1_fused<<<Mr, 256, 0, stream>>>(x, ln1g, ln1b, hlnC, vC, wvec, row0, BC, flag);
        for (int hg = 0; hg < 12; hg += HG) {
            // fused G1|vT projection: M=Mr, N=1536, K=768 (proven 128^2 kernel)
            mgemm<7, 4><<<dim3(12, gy, HG), 256, 0, stream>>>(hlnC,
                Wcomb + (long)hg * 1179648, G1C, nullptr, vTC,
                nullptr, (long)hg * 768, nullptr, bv,
                Mr, 1536, 768, 768, 768, 0, 1179648L, 0, 0, 0, 1.0f, flag);
            // fused scores+softmax: attn[z] = softmax(G1[z] @ hln[b]^T + v[s])
            mgemm<9, 8><<<dim3(1, 2, HG * BC), 256, 0, stream>>>(G1C, hlnC, attnC,
                nullptr, nullptr, nullptr, 0, vC + (long)hg * BC * 197, nullptr,
                197, 197, 768, 768, 768, 197L * 768, 197L * 768, 0, BC, 0, 1.0f, flag);
            // ao[z] = attn[z] @ vT[z]^T : M=197, N=768, K=224 -> aoTg head slice
            mgemm<3, 4><<<dim3(6, 2, HG * BC), 256, 0, stream>>>(attnC, vTC, aoTg,
                nullptr, nullptr, nullptr, 0, nullptr, nullptr,
                197, 768, 224, 224, 224, 197L * 224, 768L * 224, hg * 224, BC, 0, 1.0f, flag);
        }
        // map: split-K x4 partials, then reduce (+bmap + x) + fused ln2 -> h2All
        mgemm<8, 4><<<dim3(6, 2, BC * 4), 256, 0, stream>>>(wmpad, aoTg, part4,
            nullptr, nullptr, nullptr, 0, nullptr, nullptr,
            197, 768, 672, 2688, 2688, 0, 768L * 2688, Mr, 4, 0, 1.0f, flag);
        red4ln<<<Mr, 256, 0, stream>>>(part4, bmap, x, ln2g, ln2b, h2All, row0, Mr, flag);
    }

    // ---- MLP phase ----
    cvt_b16<<<cdiv(2359296, 256), 256, 0, stream>>>(W1, W1b, 2359296, flag);
    cvt_b16<<<cdiv(2359296, 256), 256, 0, stream>>>(W2, W2b, 2359296, flag);
    for (int r0 = 0; r0 < 6304; r0 += MC) {
        const int gy2 = cdiv(MC, 128);
        mgemm<5, 4><<<dim3(24, gy2, 1), 256, 0, stream>>>(h2All + (long)r0 * 768, W1b, gC,
            nullptr, nullptr, b1, 0, nullptr, nullptr,
            MC, 3072, 768, 768, 768, 0, 0, 0, 0, 0, 1.0f, flag);
        // mlp2: split-K x4 partials, then reduce (+b2 + h2 residual) -> d_out
        mgemm<8, 4><<<dim3(6, gy2, 4), 256, 0, stream>>>(gC, W2b, part2,
            nullptr, nullptr, nullptr, 0, nullptr, nullptr,
            MC, 768, 768, 3072, 3072, 0, 0, MC, 4, 0, 1.0f, flag);
        red6<<<MC, 256, 0, stream>>>(part2, b2, h2All + (long)r0 * 768, d_out, r0, MC, flag);
    }
}